// Round 19
// baseline (83.834 us; speedup 1.0000x reference)
//
#include <hip/hip_runtime.h>
#include <math.h>

typedef __attribute__((ext_vector_type(8))) short short8;
typedef __attribute__((ext_vector_type(8))) _Float16 f16x8;
typedef __attribute__((ext_vector_type(4))) float floatx4;
typedef __attribute__((ext_vector_type(4))) int intx4;
typedef __attribute__((ext_vector_type(16))) int intx16;

#define B_ROWS 8192
#define FIN    512
#define FOUT   512
#define QSN    4096.0f
#define QINVN  0.000244140625f
#define QSD    32768.0f

// ---- workspace byte offsets ----
#define WSB_SW   0UL
#define WSB_CNT  64UL
#define WSB_BCPK 65536UL     // 8192*512 u32: (cd_u16 << 16) | base_f16bits  [65536, 16842752)
#define WSB_XCH  16842752UL  // 8192*512 f16 cleaned x
#define WSB_MSK  25231360UL
#define WSB_WH   33619968UL
#define WSB_BCT  34144256UL
#define WSB_BCTD 36241408UL

__device__ __forceinline__ void gl2lds16(const void* g, void* l) {
    __builtin_amdgcn_global_load_lds((const __attribute__((address_space(1))) void*)g,
                                     (__attribute__((address_space(3))) void*)l,
                                     16, 0, 0);
}

__device__ __forceinline__ float frcp(float x) { float r; asm("v_rcp_f32 %0, %1" : "=v"(r) : "v"(x)); return r; }
__device__ __forceinline__ float frsq(float x) { float r; asm("v_rsq_f32 %0, %1" : "=v"(r) : "v"(x)); return r; }
__device__ __forceinline__ float fexp2(float x){ float r; asm("v_exp_f32 %0, %1" : "=v"(r) : "v"(x)); return r; }

// ---------------- merged prep (unchanged) ----------------
__global__ __launch_bounds__(256) void prep_all(const float* __restrict__ W,
                                                const float* __restrict__ mean_p,
                                                const float* __restrict__ ls2,
                                                const float* __restrict__ x,
                                                const float* __restrict__ lw,
                                                signed char* __restrict__ bct8,
                                                signed char* __restrict__ bctd,
                                                _Float16* __restrict__ Wh,
                                                _Float16* __restrict__ xch,
                                                signed char* __restrict__ msk,
                                                int* __restrict__ cnts,
                                                float* __restrict__ wsf) {
    int tid = threadIdx.x, lane = tid & 63, wid = tid >> 6;
    if (blockIdx.x < 1024) {
        int n  = blockIdx.x * 4 + wid;
        int fc = lane << 3;
        int o = n >> 3, m = n & 7;
        const float* wp = W + (size_t)o * FIN + fc;
        const float* mp = mean_p + (size_t)m * FIN + fc;
        if (m == 0) {
            f16x8 wv;
#pragma unroll
            for (int j = 0; j < 8; ++j) wv[j] = (_Float16)wp[j];
            *(f16x8*)(Wh + (size_t)o * FIN + fc) = wv;
        }
        unsigned long long pack = 0;
#pragma unroll
        for (int j = 0; j < 8; ++j) {
            int q = (int)rintf(mp[j] * wp[j] * QSN);
            q = q > 127 ? 127 : (q < -127 ? -127 : q);
            pack |= ((unsigned long long)(unsigned char)(signed char)q) << (8 * j);
        }
        *(unsigned long long*)(bct8 + (size_t)n * FIN + fc) = pack;
    } else if (blockIdx.x < 1152) {
        int o  = (blockIdx.x - 1024) * 4 + wid;
        int fc = lane << 3;
        const float* wp = W + (size_t)o * FIN + fc;
        unsigned long long pack = 0;
#pragma unroll
        for (int j = 0; j < 8; ++j) {
            float ae = 0.f;
#pragma unroll
            for (int mm = 0; mm < 8; ++mm)
                ae += fexp2(ls2[(size_t)mm * FIN + fc + j] * 1.4426950408889634f);
            ae *= 0.125f;
            int q = (int)rintf(ae * wp[j] * wp[j] * QSD);
            q = q > 127 ? 127 : (q < -127 ? -127 : q);
            pack |= ((unsigned long long)(unsigned char)(signed char)q) << (8 * j);
        }
        *(unsigned long long*)(bctd + (size_t)o * FIN + fc) = pack;
    } else {
        int row = (blockIdx.x - 1152) * 4 + wid;
        const float* xr = x + (size_t)row * FIN + lane * 8;
        float4 a = *(const float4*)xr;
        float4 b = *(const float4*)(xr + 4);
        float v[8] = {a.x, a.y, a.z, a.w, b.x, b.y, b.z, b.w};
        f16x8 xo;
        unsigned long long mpack = 0;
        bool anyn = false;
#pragma unroll
        for (int j = 0; j < 8; ++j) {
            bool isn = (v[j] != v[j]);
            anyn |= isn;
            xo[j] = (_Float16)(isn ? 0.f : v[j]);
            mpack |= ((unsigned long long)(isn ? 1u : 0u)) << (8 * j);
        }
        *(f16x8*)(xch + (size_t)row * FIN + lane * 8) = xo;
        *(unsigned long long*)(msk + (size_t)row * FIN + lane * 8) = mpack;
        bool any = __any(anyn);
        if (lane == 0) cnts[row] = any ? 1 : 0;
        if (blockIdx.x == 1152 && tid == 0) {
            float mx = lw[0];
            for (int m = 1; m < 8; ++m) mx = fmaxf(mx, lw[m]);
            float e[8]; float s = 0.f;
            for (int m = 0; m < 8; ++m) { e[m] = expf(lw[m] - mx); s += e[m]; }
            for (int m = 0; m < 8; ++m) wsf[m] = e[m] / s;
        }
    }
}

// ---------------- merged base+cd GEMM -> packed bcpk (disjoint-byte writes) ----------------
__global__ __launch_bounds__(256, 2) void gemm_bc(const _Float16* __restrict__ xch,
                                                  const _Float16* __restrict__ Wh,
                                                  const signed char* __restrict__ msk,
                                                  const signed char* __restrict__ bctd,
                                                  unsigned short* __restrict__ bcp) {  // u16 view of bcpk
    __shared__ char lds[73728];
    int tid = threadIdx.x, lane = tid & 63, wid = tid >> 6;
    int wr = wid >> 1, wc = wid & 1;
    int bb0 = blockIdx.y * 128;

    if (blockIdx.x < 8) {
        int ob0 = blockIdx.x * 64;
        const char* xB = (const char*)xch;
        const char* wB = (const char*)Wh;

        int rA0 = (wid +  0) * 8 + (lane >> 3);
        int rA1 = (wid +  4) * 8 + (lane >> 3);
        int rA2 = (wid +  8) * 8 + (lane >> 3);
        int rA3 = (wid + 12) * 8 + (lane >> 3);
        const char* gA0 = xB + (size_t)(bb0 + rA0) * 1024 + (((lane & 7) ^ (rA0 & 7)) << 4);
        const char* gA1 = xB + (size_t)(bb0 + rA1) * 1024 + (((lane & 7) ^ (rA1 & 7)) << 4);
        const char* gA2 = xB + (size_t)(bb0 + rA2) * 1024 + (((lane & 7) ^ (rA2 & 7)) << 4);
        const char* gA3 = xB + (size_t)(bb0 + rA3) * 1024 + (((lane & 7) ^ (rA3 & 7)) << 4);
        const char* gB0 = wB + (size_t)(ob0 + rA0) * 1024 + (((lane & 7) ^ (rA0 & 7)) << 4);
        const char* gB1 = wB + (size_t)(ob0 + rA1) * 1024 + (((lane & 7) ^ (rA1 & 7)) << 4);
        const int lA0o = (wid +  0) * 1024, lA1o = (wid +  4) * 1024;
        const int lA2o = (wid +  8) * 1024, lA3o = (wid + 12) * 1024;
        const int lB0o = 16384 + (wid + 0) * 1024, lB1o = 16384 + (wid + 4) * 1024;

        int offA[4], offB[2];
#pragma unroll
        for (int mi = 0; mi < 4; ++mi) {
            int r = wr * 64 + mi * 16 + (lane & 15);
            offA[mi] = r * 128 + ((((lane >> 4) ^ (r & 7))) << 4);
        }
#pragma unroll
        for (int ni = 0; ni < 2; ++ni) {
            int r = wc * 32 + ni * 16 + (lane & 15);
            offB[ni] = 16384 + r * 128 + ((((lane >> 4) ^ (r & 7))) << 4);
        }

        floatx4 acc[4][2];
#pragma unroll
        for (int mi = 0; mi < 4; ++mi)
#pragma unroll
            for (int ni = 0; ni < 2; ++ni) acc[mi][ni] = (floatx4){0.f, 0.f, 0.f, 0.f};

#define STAGEB(T)                                            \
        {                                                    \
            const int bo_ = ((T) % 3) * 24576;               \
            gl2lds16(gA0 + (T) * 128, lds + bo_ + lA0o);     \
            gl2lds16(gA1 + (T) * 128, lds + bo_ + lA1o);     \
            gl2lds16(gA2 + (T) * 128, lds + bo_ + lA2o);     \
            gl2lds16(gA3 + (T) * 128, lds + bo_ + lA3o);     \
            gl2lds16(gB0 + (T) * 128, lds + bo_ + lB0o);     \
            gl2lds16(gB1 + (T) * 128, lds + bo_ + lB1o);     \
        }

        STAGEB(0); STAGEB(1);

#pragma unroll
        for (int t = 0; t < 8; ++t) {
            if (t < 7) asm volatile("s_waitcnt vmcnt(6)" ::: "memory");
            else       asm volatile("s_waitcnt vmcnt(0)" ::: "memory");
            __builtin_amdgcn_s_barrier();
            asm volatile("" ::: "memory");
            if (t + 2 < 8) STAGEB(t + 2);

            const int bo = (t % 3) * 24576;
#pragma unroll
            for (int kk = 0; kk < 2; ++kk) {
                const int kx = kk << 6;
                f16x8 av[4], bv[2];
#pragma unroll
                for (int mi = 0; mi < 4; ++mi) av[mi] = *(const f16x8*)(lds + bo + (offA[mi] ^ kx));
#pragma unroll
                for (int ni = 0; ni < 2; ++ni) bv[ni] = *(const f16x8*)(lds + bo + (offB[ni] ^ kx));
                __builtin_amdgcn_s_setprio(1);
#pragma unroll
                for (int mi = 0; mi < 4; ++mi)
#pragma unroll
                    for (int ni = 0; ni < 2; ++ni)
                        acc[mi][ni] = __builtin_amdgcn_mfma_f32_16x16x32_f16(av[mi], bv[ni], acc[mi][ni], 0, 0, 0);
                __builtin_amdgcn_s_setprio(0);
            }
        }
#undef STAGEB

#pragma unroll
        for (int mi = 0; mi < 4; ++mi)
#pragma unroll
            for (int ni = 0; ni < 2; ++ni)
#pragma unroll
                for (int r = 0; r < 4; ++r) {
                    int row = bb0 + wr * 64 + mi * 16 + (lane >> 4) * 4 + r;
                    int col = ob0 + wc * 32 + ni * 16 + (lane & 15);
                    unsigned short hb = __builtin_bit_cast(unsigned short, (_Float16)acc[mi][ni][r]);
                    bcp[((((size_t)row << 9) + col) << 1) + 0] = hb;   // low half of bcpk dword
                }
    } else {
        int ob0 = (blockIdx.x - 8) * 64;
        const char* mB = (const char*)msk;
        const char* dB = (const char*)bctd;

        int rA0 = (wid + 0) * 16 + (lane >> 2);
        int rA1 = (wid + 4) * 16 + (lane >> 2);
        const char* gA0 = mB + (size_t)(bb0 + rA0) * 512 + (((lane & 3) ^ ((rA0 >> 1) & 3)) << 4);
        const char* gA1 = mB + (size_t)(bb0 + rA1) * 512 + (((lane & 3) ^ ((rA1 >> 1) & 3)) << 4);
        const char* gB0 = dB + (size_t)(ob0 + rA0) * 512 + (((lane & 3) ^ ((rA0 >> 1) & 3)) << 4);
        const int lA0o = (wid + 0) * 1024;
        const int lA1o = (wid + 4) * 1024;
        const int lB0o = 8192 + wid * 1024;

        int offA[2], offB;
#pragma unroll
        for (int mi = 0; mi < 2; ++mi) {
            int r = wr * 64 + mi * 32 + (lane & 31);
            offA[mi] = r * 64 + ((((lane >> 5) ^ ((r >> 1) & 3))) << 4);
        }
        {
            int r = wc * 32 + (lane & 31);
            offB = 8192 + r * 64 + ((((lane >> 5) ^ ((r >> 1) & 3))) << 4);
        }

        intx16 acc[2];
#pragma unroll
        for (int mi = 0; mi < 2; ++mi)
#pragma unroll
            for (int e = 0; e < 16; ++e) acc[mi][e] = 0;

#define STAGEC(T)                                            \
        {                                                    \
            const int bo_ = ((T) % 3) * 12288;               \
            gl2lds16(gA0 + (T) * 64, lds + bo_ + lA0o);      \
            gl2lds16(gA1 + (T) * 64, lds + bo_ + lA1o);      \
            gl2lds16(gB0 + (T) * 64, lds + bo_ + lB0o);      \
        }

        STAGEC(0); STAGEC(1);

#pragma unroll
        for (int t = 0; t < 8; ++t) {
            if (t < 7) asm volatile("s_waitcnt vmcnt(3)" ::: "memory");
            else       asm volatile("s_waitcnt vmcnt(0)" ::: "memory");
            __builtin_amdgcn_s_barrier();
            asm volatile("" ::: "memory");
            if (t + 2 < 8) STAGEC(t + 2);

            const int bo = (t % 3) * 12288;
#pragma unroll
            for (int kk = 0; kk < 2; ++kk) {
                const int kx = kk << 5;
                intx4 av[2], bv;
#pragma unroll
                for (int mi = 0; mi < 2; ++mi) av[mi] = *(const intx4*)(lds + bo + (offA[mi] ^ kx));
                bv = *(const intx4*)(lds + bo + (offB ^ kx));
                __builtin_amdgcn_s_setprio(1);
#pragma unroll
                for (int mi = 0; mi < 2; ++mi)
                    acc[mi] = __builtin_amdgcn_mfma_i32_32x32x32_i8(av[mi], bv, acc[mi], 0, 0, 0);
                __builtin_amdgcn_s_setprio(0);
            }
        }
#undef STAGEC

        __syncthreads();

        int* sci = (int*)(lds + wid * 4224);
        int cl = lane & 31, oh = lane >> 5;
#pragma unroll
        for (int mi = 0; mi < 2; ++mi) {
#pragma unroll
            for (int reg = 0; reg < 16; ++reg) {
                int r = (reg & 3) + 8 * (reg >> 2) + 4 * oh;   // b_local
                sci[r * 33 + cl] = acc[mi][reg];               // col = o_local
            }
            __asm__ volatile("s_waitcnt lgkmcnt(0)" ::: "memory");

            int b  = bb0 + wr * 64 + mi * 32 + cl;
            int og = ob0 + wc * 32 + oh * 16;
            size_t ob2 = ((size_t)b << 9) + og;
#pragma unroll
            for (int j = 0; j < 16; ++j) {
                int v = sci[cl * 33 + oh * 16 + j];
                unsigned u = (v < 0) ? 0u : (unsigned)v * 4u;
                u = (u > 65535u ? 65535u : u);
                bcp[((ob2 + j) << 1) + 1] = (unsigned short)u;   // high half of bcpk dword
            }
            __asm__ volatile("s_waitcnt lgkmcnt(0)" ::: "memory");
        }
    }
}

// ---------------- fused mask-GEMM (i8) + conflict-free f32 LUT epilogue ----------------
// out = sum_m sw[m]*max(num_m,0) + den * sum_m sw[m]*H(|z_m|),  H(a)=pdf(a)-a*Q(a)
__global__ __launch_bounds__(512, 4) void gmm_fused(const signed char* __restrict__ msk,
                                                    const signed char* __restrict__ bct8,
                                                    const float* __restrict__ wsf,
                                                    const int* __restrict__ cnts,
                                                    const unsigned int* __restrict__ bcpk,
                                                    const float* __restrict__ bias,
                                                    float* __restrict__ out) {
    __shared__ char lds[73728];   // tiles; after K-loop: [0,33792) scratch, [36864,69760) H-table

    int tid = threadIdx.x, lane = tid & 63, wid = tid >> 6;
    int wr = wid >> 1, wc = wid & 1;        // 4(M) x 2(N)
    int cl = lane & 31, oh = lane >> 5;

    // XCD-aware mapping
    int id = blockIdx.x;
    int xcd = id & 7, pos = id >> 3;
    int my = xcd * 4 + (pos & 3);
    int nx = pos >> 2;
    int b0 = my * 256, n0 = nx * 128, o0 = nx * 16;

    const char* mB = (const char*)msk;
    const char* bB = (const char*)bct8;

    int rA0 = (wid + 0) * 16 + (lane >> 2);
    int rA1 = (wid + 8) * 16 + (lane >> 2);
    const char* gA0 = mB + (size_t)(b0 + rA0) * 512 + (((lane & 3) ^ ((rA0 >> 1) & 3)) << 4);
    const char* gA1 = mB + (size_t)(b0 + rA1) * 512 + (((lane & 3) ^ ((rA1 >> 1) & 3)) << 4);
    const char* gB0 = bB + (size_t)(n0 + rA0) * 512 + (((lane & 3) ^ ((rA0 >> 1) & 3)) << 4);
    const int lA0o = (wid + 0) * 1024;
    const int lA1o = (wid + 8) * 1024;
    const int lB0o = 16384 + wid * 1024;

#define STAGE(T)                                             \
    {                                                        \
        const int bo_ = ((T) % 3) * 24576;                   \
        gl2lds16(gA0 + (T) * 64, lds + bo_ + lA0o);          \
        gl2lds16(gA1 + (T) * 64, lds + bo_ + lA1o);          \
        gl2lds16(gB0 + (T) * 64, lds + bo_ + lB0o);          \
    }

    STAGE(0);
    asm volatile("" ::: "memory");

    // epilogue scalar prefetch (drained by first vmcnt(3)): bias 4 + cnts 2 + bcpk 8 loads
    float bias_r[2][2];
    unsigned int bc_r[2][2][2];
    int cnt_r[2];
#pragma unroll
    for (int ni = 0; ni < 2; ++ni)
#pragma unroll
        for (int p = 0; p < 2; ++p)
            bias_r[ni][p] = bias[o0 + wc * 8 + ni * 4 + oh + 2 * p];
#pragma unroll
    for (int mi = 0; mi < 2; ++mi) {
        int b = b0 + wr * 64 + mi * 32 + cl;
        cnt_r[mi] = cnts[b];
#pragma unroll
        for (int ni = 0; ni < 2; ++ni)
#pragma unroll
            for (int p = 0; p < 2; ++p)
                bc_r[mi][ni][p] = bcpk[((size_t)b << 9) + o0 + wc * 8 + ni * 4 + oh + 2 * p];
    }
    asm volatile("" ::: "memory");

    STAGE(1);

    int offA[2], offB[2];
#pragma unroll
    for (int mi = 0; mi < 2; ++mi) {
        int r = wr * 64 + mi * 32 + cl;
        offA[mi] = r * 64 + (((oh ^ ((r >> 1) & 3))) << 4);
    }
#pragma unroll
    for (int ni = 0; ni < 2; ++ni) {
        int r = wc * 64 + ni * 32 + cl;
        offB[ni] = 16384 + r * 64 + (((oh ^ ((r >> 1) & 3))) << 4);
    }

    intx16 acc[2][2];
#pragma unroll
    for (int mi = 0; mi < 2; ++mi)
#pragma unroll
        for (int ni = 0; ni < 2; ++ni)
#pragma unroll
            for (int e = 0; e < 16; ++e) acc[mi][ni][e] = 0;

#pragma unroll
    for (int t = 0; t < 8; ++t) {
        if (t < 7) asm volatile("s_waitcnt vmcnt(3)" ::: "memory");
        else       asm volatile("s_waitcnt vmcnt(0)" ::: "memory");
        __builtin_amdgcn_s_barrier();
        asm volatile("" ::: "memory");
        if (t + 2 < 8) STAGE(t + 2);

        const int bo = (t % 3) * 24576;
#pragma unroll
        for (int kk = 0; kk < 2; ++kk) {
            const int kx = kk << 5;
            intx4 av[2], bv[2];
#pragma unroll
            for (int mi = 0; mi < 2; ++mi) av[mi] = *(const intx4*)(lds + bo + (offA[mi] ^ kx));
#pragma unroll
            for (int ni = 0; ni < 2; ++ni) bv[ni] = *(const intx4*)(lds + bo + (offB[ni] ^ kx));
            __builtin_amdgcn_s_setprio(1);
#pragma unroll
            for (int mi = 0; mi < 2; ++mi)
#pragma unroll
                for (int ni = 0; ni < 2; ++ni)
                    acc[mi][ni] = __builtin_amdgcn_mfma_i32_32x32x32_i8(av[mi], bv[ni], acc[mi][ni], 0, 0, 0);
            __builtin_amdgcn_s_setprio(0);
        }
    }
#undef STAGE

    __syncthreads();   // all waves done reading tile buffers

    // ---- build H(a) table: 256 f32 entries (a = i/64), 32 copies stride 1028B ----
    {
        char* tb = lds + 36864;
        int i  = tid & 255;
        int h0 = (tid >> 8) * 16;           // copies [h0, h0+16)
        float a  = (float)i * 0.015625f;
        float E  = fexp2(a * a * -0.72134752044448170f);
        float t1 = frcp(fmaf(0.2316419f, a, 1.0f));
        float h  = fmaf(t1, 0.5307027145f, -0.7265760135f);
        h = fmaf(t1, h, 0.7107068705f);
        h = fmaf(t1, h, -0.142248368f);
        h = fmaf(t1, h, 0.127414796f);
        float H  = E * fmaf(-a, t1 * h, 0.3989422804014327f);   // pdf - a*Q >= 0
#pragma unroll
        for (int c = 0; c < 16; ++c)
            *(float*)(tb + (h0 + c) * 1028 + i * 4) = H;
    }
    __syncthreads();   // table visible to all waves

    float swv[8];
#pragma unroll
    for (int m = 0; m < 8; ++m) swv[m] = wsf[m];

    const char* tbl = lds + 36864 + (lane & 31) * 1028;   // lane's copy; l & l+32 share -> 2-way (free)

    // ---- epilogue: scratch transpose + LUT mixture, results buffered in regs ----
    int* sci = (int*)(lds + wid * 4224);    // per-wave private, [0,33792)
    float val_r[8];

#pragma unroll
    for (int mi = 0; mi < 2; ++mi) {
#pragma unroll
        for (int ni = 0; ni < 2; ++ni) {
#pragma unroll
            for (int reg = 0; reg < 16; ++reg) {
                int r = (reg & 3) + 8 * (reg >> 2) + 4 * oh;   // b_local
                sci[r * 33 + cl] = acc[mi][ni][reg];           // col = n_local
            }
            __asm__ volatile("s_waitcnt lgkmcnt(0)" ::: "memory");

#pragma unroll
            for (int p = 0; p < 2; ++p) {
                int oc = oh + 2 * p;
                int cni[8];
#pragma unroll
                for (int m = 0; m < 8; ++m) cni[m] = sci[cl * 33 + oc * 8 + m];

                unsigned bc = bc_r[mi][ni][p];
                float basev = (float)__builtin_bit_cast(_Float16, (unsigned short)(bc & 0xffffu));
                float c   = (float)(bc >> 16) * 7.62939453125e-6f;   // /131072
                float rs  = frsq(fmaxf(c, 1e-20f));
                float den = c * rs;
                float K0  = basev + bias_r[ni][p];
                bool empty = cnt_r[mi] > 0;

                float gs1 = 0.f, gs2 = 0.f, num0 = 0.f;
#pragma unroll
                for (int m = 0; m < 8; ++m) {
                    float num = fmaf((float)cni[m], QINVN, K0);
                    if (m == 0) num0 = num;
                    float az = fabsf(num) * rs;
                    float uu = fminf(fmaf(az, 64.0f, 0.5f), 255.0f);
                    int idx  = (int)uu;
                    float Hf = *(const float*)(tbl + idx * 4);
                    gs1 = fmaf(swv[m], fmaxf(num, 0.f), gs1);
                    gs2 = fmaf(swv[m], Hf, gs2);
                }
                val_r[mi * 4 + ni * 2 + p] = empty ? fmaf(den, gs2, gs1) : fmaxf(num0, 0.f);
            }
            __asm__ volatile("s_waitcnt lgkmcnt(0)" ::: "memory");
        }
    }

    // ---- pack to scratch [64 b][stride 9] f32 and store coalesced ----
    float* scf = (float*)(lds + wid * 4224);
#pragma unroll
    for (int mi = 0; mi < 2; ++mi)
#pragma unroll
        for (int ni = 0; ni < 2; ++ni)
#pragma unroll
            for (int p = 0; p < 2; ++p)
                scf[(mi * 32 + cl) * 9 + ni * 4 + oh + 2 * p] = val_r[mi * 4 + ni * 2 + p];
    __asm__ volatile("s_waitcnt lgkmcnt(0)" ::: "memory");

    const size_t obase = ((size_t)(b0 + wr * 64) << 9) + o0 + wc * 8;
#pragma unroll
    for (int pass = 0; pass < 8; ++pass) {
        int row = pass * 8 + (lane >> 3);
        int h   = lane & 7;
        float v = scf[row * 9 + h];
        out[obase + ((size_t)row << 9) + h] = v;
    }
}

extern "C" void kernel_launch(void* const* d_in, const int* in_sizes, int n_in,
                              void* d_out, int out_size, void* d_ws, size_t ws_size,
                              hipStream_t stream) {
    const float* x        = (const float*)d_in[0];
    const float* W        = (const float*)d_in[1];
    const float* bvec     = (const float*)d_in[2];
    const float* mean_p   = (const float*)d_in[3];
    const float* log_std2 = (const float*)d_in[4];
    const float* lw       = (const float*)d_in[5];
    float* out = (float*)d_out;

    char* wsb = (char*)d_ws;
    float*          wsf  = (float*)wsb;
    int*            cnts = (int*)(wsb + WSB_CNT);
    unsigned short* bcp  = (unsigned short*)(wsb + WSB_BCPK);
    unsigned int*   bcpk = (unsigned int*)(wsb + WSB_BCPK);
    _Float16*       xch  = (_Float16*)(wsb + WSB_XCH);
    signed char*    msk  = (signed char*)(wsb + WSB_MSK);
    _Float16*       Wh   = (_Float16*)(wsb + WSB_WH);
    signed char*    bct8 = (signed char*)(wsb + WSB_BCT);
    signed char*    bctd = (signed char*)(wsb + WSB_BCTD);

    prep_all<<<3200, 256, 0, stream>>>(W, mean_p, log_std2, x, lw, bct8, bctd, Wh, xch, msk, cnts, wsf);
    gemm_bc<<<dim3(16, B_ROWS / 128), 256, 0, stream>>>(xch, Wh, msk, bctd, bcp);
    gmm_fused<<<1024, 512, 0, stream>>>(msk, bct8, wsf, cnts, bcpk, bvec, out);
}

// Round 20
// 71.081 us; speedup vs baseline: 1.1794x; 1.1794x over previous
//
#include <hip/hip_runtime.h>
#include <math.h>

typedef __attribute__((ext_vector_type(8))) short short8;
typedef __attribute__((ext_vector_type(8))) _Float16 f16x8;
typedef __attribute__((ext_vector_type(4))) float floatx4;
typedef __attribute__((ext_vector_type(4))) int intx4;
typedef __attribute__((ext_vector_type(16))) int intx16;
typedef __attribute__((ext_vector_type(8))) unsigned short ushort8;

#define B_ROWS 8192
#define FIN    512
#define FOUT   512
#define QSN    4096.0f
#define QINVN  0.000244140625f
#define QSD    32768.0f

// ---- workspace byte offsets ----
#define WSB_SW   0UL
#define WSB_CNT  64UL
#define WSB_BASE 65536UL     // 8192*512 f16, ends at 8454144
#define WSB_CDU  8454144UL   // 8192*512 u16 cd = cdi*4 (lossless), dedicated (no aliasing)
#define WSB_XCH  16842752UL  // 8192*512 f16 cleaned x
#define WSB_MSK  25231360UL
#define WSB_WH   33619968UL
#define WSB_BCT  34144256UL
#define WSB_BCTD 36241408UL

__device__ __forceinline__ void gl2lds16(const void* g, void* l) {
    __builtin_amdgcn_global_load_lds((const __attribute__((address_space(1))) void*)g,
                                     (__attribute__((address_space(3))) void*)l,
                                     16, 0, 0);
}

__device__ __forceinline__ float frcp(float x) { float r; asm("v_rcp_f32 %0, %1" : "=v"(r) : "v"(x)); return r; }
__device__ __forceinline__ float frsq(float x) { float r; asm("v_rsq_f32 %0, %1" : "=v"(r) : "v"(x)); return r; }
__device__ __forceinline__ float fexp2(float x){ float r; asm("v_exp_f32 %0, %1" : "=v"(r) : "v"(x)); return r; }

// ---------------- merged prep (unchanged) ----------------
__global__ __launch_bounds__(256) void prep_all(const float* __restrict__ W,
                                                const float* __restrict__ mean_p,
                                                const float* __restrict__ ls2,
                                                const float* __restrict__ x,
                                                const float* __restrict__ lw,
                                                signed char* __restrict__ bct8,
                                                signed char* __restrict__ bctd,
                                                _Float16* __restrict__ Wh,
                                                _Float16* __restrict__ xch,
                                                signed char* __restrict__ msk,
                                                int* __restrict__ cnts,
                                                float* __restrict__ wsf) {
    int tid = threadIdx.x, lane = tid & 63, wid = tid >> 6;
    if (blockIdx.x < 1024) {
        int n  = blockIdx.x * 4 + wid;
        int fc = lane << 3;
        int o = n >> 3, m = n & 7;
        const float* wp = W + (size_t)o * FIN + fc;
        const float* mp = mean_p + (size_t)m * FIN + fc;
        if (m == 0) {
            f16x8 wv;
#pragma unroll
            for (int j = 0; j < 8; ++j) wv[j] = (_Float16)wp[j];
            *(f16x8*)(Wh + (size_t)o * FIN + fc) = wv;
        }
        unsigned long long pack = 0;
#pragma unroll
        for (int j = 0; j < 8; ++j) {
            int q = (int)rintf(mp[j] * wp[j] * QSN);
            q = q > 127 ? 127 : (q < -127 ? -127 : q);
            pack |= ((unsigned long long)(unsigned char)(signed char)q) << (8 * j);
        }
        *(unsigned long long*)(bct8 + (size_t)n * FIN + fc) = pack;
    } else if (blockIdx.x < 1152) {
        int o  = (blockIdx.x - 1024) * 4 + wid;
        int fc = lane << 3;
        const float* wp = W + (size_t)o * FIN + fc;
        unsigned long long pack = 0;
#pragma unroll
        for (int j = 0; j < 8; ++j) {
            float ae = 0.f;
#pragma unroll
            for (int mm = 0; mm < 8; ++mm)
                ae += fexp2(ls2[(size_t)mm * FIN + fc + j] * 1.4426950408889634f);
            ae *= 0.125f;
            int q = (int)rintf(ae * wp[j] * wp[j] * QSD);
            q = q > 127 ? 127 : (q < -127 ? -127 : q);
            pack |= ((unsigned long long)(unsigned char)(signed char)q) << (8 * j);
        }
        *(unsigned long long*)(bctd + (size_t)o * FIN + fc) = pack;
    } else {
        int row = (blockIdx.x - 1152) * 4 + wid;
        const float* xr = x + (size_t)row * FIN + lane * 8;
        float4 a = *(const float4*)xr;
        float4 b = *(const float4*)(xr + 4);
        float v[8] = {a.x, a.y, a.z, a.w, b.x, b.y, b.z, b.w};
        f16x8 xo;
        unsigned long long mpack = 0;
        bool anyn = false;
#pragma unroll
        for (int j = 0; j < 8; ++j) {
            bool isn = (v[j] != v[j]);
            anyn |= isn;
            xo[j] = (_Float16)(isn ? 0.f : v[j]);
            mpack |= ((unsigned long long)(isn ? 1u : 0u)) << (8 * j);
        }
        *(f16x8*)(xch + (size_t)row * FIN + lane * 8) = xo;
        *(unsigned long long*)(msk + (size_t)row * FIN + lane * 8) = mpack;
        bool any = __any(anyn);
        if (lane == 0) cnts[row] = any ? 1 : 0;
        if (blockIdx.x == 1152 && tid == 0) {
            float mx = lw[0];
            for (int m = 1; m < 8; ++m) mx = fmaxf(mx, lw[m]);
            float e[8]; float s = 0.f;
            for (int m = 0; m < 8; ++m) { e[m] = expf(lw[m] - mx); s += e[m]; }
            for (int m = 0; m < 8; ++m) wsf[m] = e[m] / s;
        }
    }
}

// ---------------- merged base+cd GEMM (r18-proven form) ----------------
__global__ __launch_bounds__(256, 2) void gemm_bc(const _Float16* __restrict__ xch,
                                                  const _Float16* __restrict__ Wh,
                                                  _Float16* __restrict__ base,
                                                  const signed char* __restrict__ msk,
                                                  const signed char* __restrict__ bctd,
                                                  unsigned short* __restrict__ cdu) {
    __shared__ char lds[73728];
    int tid = threadIdx.x, lane = tid & 63, wid = tid >> 6;
    int wr = wid >> 1, wc = wid & 1;
    int bb0 = blockIdx.y * 128;

    if (blockIdx.x < 8) {
        int ob0 = blockIdx.x * 64;
        const char* xB = (const char*)xch;
        const char* wB = (const char*)Wh;

        int rA0 = (wid +  0) * 8 + (lane >> 3);
        int rA1 = (wid +  4) * 8 + (lane >> 3);
        int rA2 = (wid +  8) * 8 + (lane >> 3);
        int rA3 = (wid + 12) * 8 + (lane >> 3);
        const char* gA0 = xB + (size_t)(bb0 + rA0) * 1024 + (((lane & 7) ^ (rA0 & 7)) << 4);
        const char* gA1 = xB + (size_t)(bb0 + rA1) * 1024 + (((lane & 7) ^ (rA1 & 7)) << 4);
        const char* gA2 = xB + (size_t)(bb0 + rA2) * 1024 + (((lane & 7) ^ (rA2 & 7)) << 4);
        const char* gA3 = xB + (size_t)(bb0 + rA3) * 1024 + (((lane & 7) ^ (rA3 & 7)) << 4);
        const char* gB0 = wB + (size_t)(ob0 + rA0) * 1024 + (((lane & 7) ^ (rA0 & 7)) << 4);
        const char* gB1 = wB + (size_t)(ob0 + rA1) * 1024 + (((lane & 7) ^ (rA1 & 7)) << 4);
        const int lA0o = (wid +  0) * 1024, lA1o = (wid +  4) * 1024;
        const int lA2o = (wid +  8) * 1024, lA3o = (wid + 12) * 1024;
        const int lB0o = 16384 + (wid + 0) * 1024, lB1o = 16384 + (wid + 4) * 1024;

        int offA[4], offB[2];
#pragma unroll
        for (int mi = 0; mi < 4; ++mi) {
            int r = wr * 64 + mi * 16 + (lane & 15);
            offA[mi] = r * 128 + ((((lane >> 4) ^ (r & 7))) << 4);
        }
#pragma unroll
        for (int ni = 0; ni < 2; ++ni) {
            int r = wc * 32 + ni * 16 + (lane & 15);
            offB[ni] = 16384 + r * 128 + ((((lane >> 4) ^ (r & 7))) << 4);
        }

        floatx4 acc[4][2];
#pragma unroll
        for (int mi = 0; mi < 4; ++mi)
#pragma unroll
            for (int ni = 0; ni < 2; ++ni) acc[mi][ni] = (floatx4){0.f, 0.f, 0.f, 0.f};

#define STAGEB(T)                                            \
        {                                                    \
            const int bo_ = ((T) % 3) * 24576;               \
            gl2lds16(gA0 + (T) * 128, lds + bo_ + lA0o);     \
            gl2lds16(gA1 + (T) * 128, lds + bo_ + lA1o);     \
            gl2lds16(gA2 + (T) * 128, lds + bo_ + lA2o);     \
            gl2lds16(gA3 + (T) * 128, lds + bo_ + lA3o);     \
            gl2lds16(gB0 + (T) * 128, lds + bo_ + lB0o);     \
            gl2lds16(gB1 + (T) * 128, lds + bo_ + lB1o);     \
        }

        STAGEB(0); STAGEB(1);

#pragma unroll
        for (int t = 0; t < 8; ++t) {
            if (t < 7) asm volatile("s_waitcnt vmcnt(6)" ::: "memory");
            else       asm volatile("s_waitcnt vmcnt(0)" ::: "memory");
            __builtin_amdgcn_s_barrier();
            asm volatile("" ::: "memory");
            if (t + 2 < 8) STAGEB(t + 2);

            const int bo = (t % 3) * 24576;
#pragma unroll
            for (int kk = 0; kk < 2; ++kk) {
                const int kx = kk << 6;
                f16x8 av[4], bv[2];
#pragma unroll
                for (int mi = 0; mi < 4; ++mi) av[mi] = *(const f16x8*)(lds + bo + (offA[mi] ^ kx));
#pragma unroll
                for (int ni = 0; ni < 2; ++ni) bv[ni] = *(const f16x8*)(lds + bo + (offB[ni] ^ kx));
                __builtin_amdgcn_s_setprio(1);
#pragma unroll
                for (int mi = 0; mi < 4; ++mi)
#pragma unroll
                    for (int ni = 0; ni < 2; ++ni)
                        acc[mi][ni] = __builtin_amdgcn_mfma_f32_16x16x32_f16(av[mi], bv[ni], acc[mi][ni], 0, 0, 0);
                __builtin_amdgcn_s_setprio(0);
            }
        }
#undef STAGEB

#pragma unroll
        for (int mi = 0; mi < 4; ++mi)
#pragma unroll
            for (int ni = 0; ni < 2; ++ni)
#pragma unroll
                for (int r = 0; r < 4; ++r) {
                    int row = bb0 + wr * 64 + mi * 16 + (lane >> 4) * 4 + r;
                    int col = ob0 + wc * 32 + ni * 16 + (lane & 15);
                    base[((size_t)row << 9) + col] = (_Float16)acc[mi][ni][r];
                }
    } else {
        int ob0 = (blockIdx.x - 8) * 64;
        const char* mB = (const char*)msk;
        const char* dB = (const char*)bctd;

        int rA0 = (wid + 0) * 16 + (lane >> 2);
        int rA1 = (wid + 4) * 16 + (lane >> 2);
        const char* gA0 = mB + (size_t)(bb0 + rA0) * 512 + (((lane & 3) ^ ((rA0 >> 1) & 3)) << 4);
        const char* gA1 = mB + (size_t)(bb0 + rA1) * 512 + (((lane & 3) ^ ((rA1 >> 1) & 3)) << 4);
        const char* gB0 = dB + (size_t)(ob0 + rA0) * 512 + (((lane & 3) ^ ((rA0 >> 1) & 3)) << 4);
        const int lA0o = (wid + 0) * 1024;
        const int lA1o = (wid + 4) * 1024;
        const int lB0o = 8192 + wid * 1024;

        int offA[2], offB;
#pragma unroll
        for (int mi = 0; mi < 2; ++mi) {
            int r = wr * 64 + mi * 32 + (lane & 31);
            offA[mi] = r * 64 + ((((lane >> 5) ^ ((r >> 1) & 3))) << 4);
        }
        {
            int r = wc * 32 + (lane & 31);
            offB = 8192 + r * 64 + ((((lane >> 5) ^ ((r >> 1) & 3))) << 4);
        }

        intx16 acc[2];
#pragma unroll
        for (int mi = 0; mi < 2; ++mi)
#pragma unroll
            for (int e = 0; e < 16; ++e) acc[mi][e] = 0;

#define STAGEC(T)                                            \
        {                                                    \
            const int bo_ = ((T) % 3) * 12288;               \
            gl2lds16(gA0 + (T) * 64, lds + bo_ + lA0o);      \
            gl2lds16(gA1 + (T) * 64, lds + bo_ + lA1o);      \
            gl2lds16(gB0 + (T) * 64, lds + bo_ + lB0o);      \
        }

        STAGEC(0); STAGEC(1);

#pragma unroll
        for (int t = 0; t < 8; ++t) {
            if (t < 7) asm volatile("s_waitcnt vmcnt(3)" ::: "memory");
            else       asm volatile("s_waitcnt vmcnt(0)" ::: "memory");
            __builtin_amdgcn_s_barrier();
            asm volatile("" ::: "memory");
            if (t + 2 < 8) STAGEC(t + 2);

            const int bo = (t % 3) * 12288;
#pragma unroll
            for (int kk = 0; kk < 2; ++kk) {
                const int kx = kk << 5;
                intx4 av[2], bv;
#pragma unroll
                for (int mi = 0; mi < 2; ++mi) av[mi] = *(const intx4*)(lds + bo + (offA[mi] ^ kx));
                bv = *(const intx4*)(lds + bo + (offB ^ kx));
                __builtin_amdgcn_s_setprio(1);
#pragma unroll
                for (int mi = 0; mi < 2; ++mi)
                    acc[mi] = __builtin_amdgcn_mfma_i32_32x32x32_i8(av[mi], bv, acc[mi], 0, 0, 0);
                __builtin_amdgcn_s_setprio(0);
            }
        }
#undef STAGEC

        __syncthreads();

        int* sci = (int*)(lds + wid * 4224);
        int cl = lane & 31, oh = lane >> 5;
#pragma unroll
        for (int mi = 0; mi < 2; ++mi) {
#pragma unroll
            for (int reg = 0; reg < 16; ++reg) {
                int r = (reg & 3) + 8 * (reg >> 2) + 4 * oh;   // b_local
                sci[r * 33 + cl] = acc[mi][reg];               // col = o_local
            }
            __asm__ volatile("s_waitcnt lgkmcnt(0)" ::: "memory");

            ushort8 g0, g1;
#pragma unroll
            for (int j = 0; j < 8; ++j) {
                int v = sci[cl * 33 + oh * 16 + j];
                unsigned u = (v < 0) ? 0u : (unsigned)v * 4u;
                g0[j] = (unsigned short)(u > 65535u ? 65535u : u);
            }
#pragma unroll
            for (int j = 0; j < 8; ++j) {
                int v = sci[cl * 33 + oh * 16 + 8 + j];
                unsigned u = (v < 0) ? 0u : (unsigned)v * 4u;
                g1[j] = (unsigned short)(u > 65535u ? 65535u : u);
            }
            int b  = bb0 + wr * 64 + mi * 32 + cl;
            int og = ob0 + wc * 32 + oh * 16;
            *(ushort8*)(cdu + ((size_t)b << 9) + og)     = g0;
            *(ushort8*)(cdu + ((size_t)b << 9) + og + 8) = g1;
            __asm__ volatile("s_waitcnt lgkmcnt(0)" ::: "memory");
        }
    }
}

// ---------------- fused mask-GEMM (i8) + conflict-free f32 LUT epilogue ----------------
// out = sum_m sw[m]*max(num_m,0) + den * sum_m sw[m]*H(|z_m|),  H(a)=pdf(a)-a*Q(a)
__global__ __launch_bounds__(512, 4) void gmm_fused(const signed char* __restrict__ msk,
                                                    const signed char* __restrict__ bct8,
                                                    const float* __restrict__ wsf,
                                                    const int* __restrict__ cnts,
                                                    const _Float16* __restrict__ baseh,
                                                    const unsigned short* __restrict__ cdu,
                                                    const float* __restrict__ bias,
                                                    float* __restrict__ out) {
    __shared__ char lds[73728];   // tiles; after K-loop: [0,33792) scratch, [36864,69760) H-table

    int tid = threadIdx.x, lane = tid & 63, wid = tid >> 6;
    int wr = wid >> 1, wc = wid & 1;        // 4(M) x 2(N)
    int cl = lane & 31, oh = lane >> 5;

    // XCD-aware mapping
    int id = blockIdx.x;
    int xcd = id & 7, pos = id >> 3;
    int my = xcd * 4 + (pos & 3);
    int nx = pos >> 2;
    int b0 = my * 256, n0 = nx * 128, o0 = nx * 16;

    const char* mB = (const char*)msk;
    const char* bB = (const char*)bct8;

    int rA0 = (wid + 0) * 16 + (lane >> 2);
    int rA1 = (wid + 8) * 16 + (lane >> 2);
    const char* gA0 = mB + (size_t)(b0 + rA0) * 512 + (((lane & 3) ^ ((rA0 >> 1) & 3)) << 4);
    const char* gA1 = mB + (size_t)(b0 + rA1) * 512 + (((lane & 3) ^ ((rA1 >> 1) & 3)) << 4);
    const char* gB0 = bB + (size_t)(n0 + rA0) * 512 + (((lane & 3) ^ ((rA0 >> 1) & 3)) << 4);
    const int lA0o = (wid + 0) * 1024;
    const int lA1o = (wid + 8) * 1024;
    const int lB0o = 16384 + wid * 1024;

#define STAGE(T)                                             \
    {                                                        \
        const int bo_ = ((T) % 3) * 24576;                   \
        gl2lds16(gA0 + (T) * 64, lds + bo_ + lA0o);          \
        gl2lds16(gA1 + (T) * 64, lds + bo_ + lA1o);          \
        gl2lds16(gB0 + (T) * 64, lds + bo_ + lB0o);          \
    }

    STAGE(0);
    asm volatile("" ::: "memory");

    // epilogue scalar prefetch (drained by first vmcnt(3))
    float bias_r[2][2];
    _Float16 base_r[2][2][2];
    unsigned short cd_r[2][2][2];
    int cnt_r[2];
#pragma unroll
    for (int ni = 0; ni < 2; ++ni)
#pragma unroll
        for (int p = 0; p < 2; ++p)
            bias_r[ni][p] = bias[o0 + wc * 8 + ni * 4 + oh + 2 * p];
#pragma unroll
    for (int mi = 0; mi < 2; ++mi) {
        int b = b0 + wr * 64 + mi * 32 + cl;
        cnt_r[mi] = cnts[b];
#pragma unroll
        for (int ni = 0; ni < 2; ++ni)
#pragma unroll
            for (int p = 0; p < 2; ++p) {
                size_t idx = ((size_t)b << 9) + o0 + wc * 8 + ni * 4 + oh + 2 * p;
                base_r[mi][ni][p] = baseh[idx];
                cd_r[mi][ni][p]   = cdu[idx];
            }
    }
    asm volatile("" ::: "memory");

    STAGE(1);

    int offA[2], offB[2];
#pragma unroll
    for (int mi = 0; mi < 2; ++mi) {
        int r = wr * 64 + mi * 32 + cl;
        offA[mi] = r * 64 + (((oh ^ ((r >> 1) & 3))) << 4);
    }
#pragma unroll
    for (int ni = 0; ni < 2; ++ni) {
        int r = wc * 64 + ni * 32 + cl;
        offB[ni] = 16384 + r * 64 + (((oh ^ ((r >> 1) & 3))) << 4);
    }

    intx16 acc[2][2];
#pragma unroll
    for (int mi = 0; mi < 2; ++mi)
#pragma unroll
        for (int ni = 0; ni < 2; ++ni)
#pragma unroll
            for (int e = 0; e < 16; ++e) acc[mi][ni][e] = 0;

#pragma unroll
    for (int t = 0; t < 8; ++t) {
        if (t < 7) asm volatile("s_waitcnt vmcnt(3)" ::: "memory");
        else       asm volatile("s_waitcnt vmcnt(0)" ::: "memory");
        __builtin_amdgcn_s_barrier();
        asm volatile("" ::: "memory");
        if (t + 2 < 8) STAGE(t + 2);

        const int bo = (t % 3) * 24576;
#pragma unroll
        for (int kk = 0; kk < 2; ++kk) {
            const int kx = kk << 5;
            intx4 av[2], bv[2];
#pragma unroll
            for (int mi = 0; mi < 2; ++mi) av[mi] = *(const intx4*)(lds + bo + (offA[mi] ^ kx));
#pragma unroll
            for (int ni = 0; ni < 2; ++ni) bv[ni] = *(const intx4*)(lds + bo + (offB[ni] ^ kx));
            __builtin_amdgcn_s_setprio(1);
#pragma unroll
            for (int mi = 0; mi < 2; ++mi)
#pragma unroll
                for (int ni = 0; ni < 2; ++ni)
                    acc[mi][ni] = __builtin_amdgcn_mfma_i32_32x32x32_i8(av[mi], bv[ni], acc[mi][ni], 0, 0, 0);
            __builtin_amdgcn_s_setprio(0);
        }
    }
#undef STAGE

    __syncthreads();   // all waves done reading tile buffers

    // ---- build H(a) table: 256 f32 entries (a = i/64), 32 copies stride 1028B ----
    {
        char* tb = lds + 36864;
        int i  = tid & 255;
        int h0 = (tid >> 8) * 16;           // copies [h0, h0+16)
        float a  = (float)i * 0.015625f;
        float E  = fexp2(a * a * -0.72134752044448170f);
        float t1 = frcp(fmaf(0.2316419f, a, 1.0f));
        float h  = fmaf(t1, 0.5307027145f, -0.7265760135f);
        h = fmaf(t1, h, 0.7107068705f);
        h = fmaf(t1, h, -0.142248368f);
        h = fmaf(t1, h, 0.127414796f);
        float H  = E * fmaf(-a, t1 * h, 0.3989422804014327f);   // pdf - a*Q >= 0
#pragma unroll
        for (int c = 0; c < 16; ++c)
            *(float*)(tb + (h0 + c) * 1028 + i * 4) = H;
    }
    __syncthreads();   // table visible to all waves

    float swv[8];
#pragma unroll
    for (int m = 0; m < 8; ++m) swv[m] = wsf[m];

    const char* tbl = lds + 36864 + (lane & 31) * 1028;   // lanes l, l+32 share a copy -> 2-way (free)

    // ---- epilogue: scratch transpose + LUT mixture, results buffered in regs ----
    int* sci = (int*)(lds + wid * 4224);    // per-wave private, [0,33792)
    float val_r[8];

#pragma unroll
    for (int mi = 0; mi < 2; ++mi) {
#pragma unroll
        for (int ni = 0; ni < 2; ++ni) {
#pragma unroll
            for (int reg = 0; reg < 16; ++reg) {
                int r = (reg & 3) + 8 * (reg >> 2) + 4 * oh;   // b_local
                sci[r * 33 + cl] = acc[mi][ni][reg];           // col = n_local
            }
            __asm__ volatile("s_waitcnt lgkmcnt(0)" ::: "memory");

#pragma unroll
            for (int p = 0; p < 2; ++p) {
                int oc = oh + 2 * p;
                int cni[8];
#pragma unroll
                for (int m = 0; m < 8; ++m) cni[m] = sci[cl * 33 + oc * 8 + m];

                float c   = (float)cd_r[mi][ni][p] * 7.62939453125e-6f;   // /131072
                float rs  = frsq(fmaxf(c, 1e-20f));
                float den = c * rs;
                float K0  = (float)base_r[mi][ni][p] + bias_r[ni][p];
                bool empty = cnt_r[mi] > 0;

                float gs1 = 0.f, gs2 = 0.f, num0 = 0.f;
#pragma unroll
                for (int m = 0; m < 8; ++m) {
                    float num = fmaf((float)cni[m], QINVN, K0);
                    if (m == 0) num0 = num;
                    float az = fabsf(num) * rs;
                    float uu = fminf(fmaf(az, 64.0f, 0.5f), 255.0f);
                    int idx  = (int)uu;
                    float Hf = *(const float*)(tbl + idx * 4);
                    gs1 = fmaf(swv[m], fmaxf(num, 0.f), gs1);
                    gs2 = fmaf(swv[m], Hf, gs2);
                }
                val_r[mi * 4 + ni * 2 + p] = empty ? fmaf(den, gs2, gs1) : fmaxf(num0, 0.f);
            }
            __asm__ volatile("s_waitcnt lgkmcnt(0)" ::: "memory");
        }
    }

    // ---- pack to scratch [64 b][stride 9] f32 and store coalesced ----
    float* scf = (float*)(lds + wid * 4224);
#pragma unroll
    for (int mi = 0; mi < 2; ++mi)
#pragma unroll
        for (int ni = 0; ni < 2; ++ni)
#pragma unroll
            for (int p = 0; p < 2; ++p)
                scf[(mi * 32 + cl) * 9 + ni * 4 + oh + 2 * p] = val_r[mi * 4 + ni * 2 + p];
    __asm__ volatile("s_waitcnt lgkmcnt(0)" ::: "memory");

    const size_t obase = ((size_t)(b0 + wr * 64) << 9) + o0 + wc * 8;
#pragma unroll
    for (int pass = 0; pass < 8; ++pass) {
        int row = pass * 8 + (lane >> 3);
        int h   = lane & 7;
        float v = scf[row * 9 + h];
        out[obase + ((size_t)row << 9) + h] = v;
    }
}

extern "C" void kernel_launch(void* const* d_in, const int* in_sizes, int n_in,
                              void* d_out, int out_size, void* d_ws, size_t ws_size,
                              hipStream_t stream) {
    const float* x        = (const float*)d_in[0];
    const float* W        = (const float*)d_in[1];
    const float* bvec     = (const float*)d_in[2];
    const float* mean_p   = (const float*)d_in[3];
    const float* log_std2 = (const float*)d_in[4];
    const float* lw       = (const float*)d_in[5];
    float* out = (float*)d_out;

    char* wsb = (char*)d_ws;
    float*          wsf  = (float*)wsb;
    int*            cnts = (int*)(wsb + WSB_CNT);
    _Float16*       base = (_Float16*)(wsb + WSB_BASE);
    _Float16*       xch  = (_Float16*)(wsb + WSB_XCH);
    signed char*    msk  = (signed char*)(wsb + WSB_MSK);
    _Float16*       Wh   = (_Float16*)(wsb + WSB_WH);
    signed char*    bct8 = (signed char*)(wsb + WSB_BCT);
    signed char*    bctd = (signed char*)(wsb + WSB_BCTD);
    unsigned short* cdu  = (unsigned short*)(wsb + WSB_CDU);

    prep_all<<<3200, 256, 0, stream>>>(W, mean_p, log_std2, x, lw, bct8, bctd, Wh, xch, msk, cnts, wsf);
    gemm_bc<<<dim3(16, B_ROWS / 128), 256, 0, stream>>>(xch, Wh, base, msk, bctd, cdu);
    gmm_fused<<<1024, 512, 0, stream>>>(msk, bct8, wsf, cnts, base, cdu, bvec, out);
}